// Round 4
// baseline (718.292 us; speedup 1.0000x reference)
//
#include <hip/hip_runtime.h>
#include <stdint.h>

#define B_  2
#define T_  2048
#define D_  1024
#define H_  16
#define HD_ 64
#define M_  (B_*T_)      // 4096
#define CHK 128          // time chunk
#define NC  (T_/CHK)     // 16
#define BH  (B_*H_)      // 32

#define XN   4194304     // x elems (4 M)
#define WN   1048576     // one W elems (1 M)

#define GRID_BLOCKS 512

typedef unsigned short ushort_t;
typedef unsigned int   uint_t;

typedef __bf16 bf16x8 __attribute__((ext_vector_type(8)));
typedef float  f32x4  __attribute__((ext_vector_type(4)));

// ---------- bf16 helpers ----------
__device__ inline ushort_t f2bf(float f) {
    uint_t x = __float_as_uint(f);
    x += 0x7fffu + ((x >> 16) & 1u);   // RNE
    return (ushort_t)(x >> 16);
}

__device__ inline uint4 pack8(const float4& lo, const float4& hi) {
    uint4 pk;
    pk.x = (uint_t)f2bf(lo.x) | ((uint_t)f2bf(lo.y) << 16);
    pk.y = (uint_t)f2bf(lo.z) | ((uint_t)f2bf(lo.w) << 16);
    pk.z = (uint_t)f2bf(hi.x) | ((uint_t)f2bf(hi.y) << 16);
    pk.w = (uint_t)f2bf(hi.z) | ((uint_t)f2bf(hi.w) << 16);
    return pk;
}

// ---------- software grid barrier (graph-capture legal, no coop launch) ----------
// Monotonic counter per sync point (memset to 0 each replay by captured memset).
// Agent-scope release/acquire handles cross-XCD L2 visibility (Guideline 16).
// Bounded spin: co-residency is guaranteed by construction (512 blocks, 2/CU),
// but if it ever breaks we fail with wrong results instead of deadlocking.
__device__ inline void grid_sync_sw(uint_t* cnt) {
    __syncthreads();
    if (threadIdx.x == 0) {
        __threadfence();   // release my block's writes
        __hip_atomic_fetch_add(cnt, 1u, __ATOMIC_ACQ_REL, __HIP_MEMORY_SCOPE_AGENT);
        int spins = 0;
        while (__hip_atomic_load(cnt, __ATOMIC_ACQUIRE, __HIP_MEMORY_SCOPE_AGENT)
               < (uint_t)GRID_BLOCKS) {
            if (++spins > (1 << 21)) break;   // failsafe, ~0.2 s
            __builtin_amdgcn_s_sleep(1);
        }
    }
    __syncthreads();
    __threadfence();       // acquire: invalidate L1/L2 so we see remote writes
}

// ---------------- m97-style staging: 8 rows (64 k-elems each) per issue ----------------
__device__ inline void stage_rows(const ushort_t* __restrict__ g, ushort_t* ldsw,
                                  int lane, int issues) {
    const int rr  = lane >> 3;
    const int kg8 = ((lane & 7) ^ rr) << 3;
    const ushort_t* src = g + (size_t)rr * D_ + kg8;
    #pragma unroll
    for (int i = 0; i < issues; i++) {
        __builtin_amdgcn_global_load_lds(
            (const __attribute__((address_space(1))) void*)(src + (size_t)(i * 8) * D_),
            (__attribute__((address_space(3))) void*)(ldsw + i * 512),
            16, 0, 0);
    }
}

#define LDS_ 136   // row stride (ushorts): 272 B = 68 dwords = 4-bank rotation

// swizzled transpose scatter: [128][64] bf16 tile -> dst[col p][136] with
// blk = (sb&8) | ((sb ^ (p>>3)) & 7).  512-thread version, 2 uint4/thread.
__device__ inline void stage_T512(const ushort_t* __restrict__ src, ushort_t* dst, int tid) {
    uint4 u[2];
    #pragma unroll
    for (int g = 0; g < 2; g++) u[g] = ((const uint4*)src)[tid + 512 * g];
    #pragma unroll
    for (int g = 0; g < 2; g++) {
        const int v  = tid + 512 * g;
        const int s  = v >> 3;
        const int p8 = (v & 7) * 8;
        ushort_t e[8];
        *(uint4*)e = u[g];
        const int sb = s >> 3, slo = s & 7;
        #pragma unroll
        for (int j = 0; j < 8; j++) {
            const int p   = p8 + j;
            const int blk = (sb & 8) | ((sb ^ (p >> 3)) & 7);
            dst[p * LDS_ + (blk << 3) + slo] = e[j];
        }
    }
}

// =======================================================================
// Single fused kernel: grid 512 x 512 thr, 2 blocks/CU (all co-resident).
// Stages: cvt -> gemm_qkv(z-fused) -> chunk_delta -> states_prefix ->
//         attn_chunk -> gemm_out, separated by software grid barriers.
// LDS union: max carve = 26112 ushorts (52224 B) -> 2 blocks/CU fits.
// =======================================================================
__global__ __launch_bounds__(512, 4) void fused_all(
    const float* __restrict__ x,  const float* __restrict__ Wq,
    const float* __restrict__ bq, const float* __restrict__ Wk,
    const float* __restrict__ bk, const float* __restrict__ Wv,
    const float* __restrict__ bv, const float* __restrict__ Wo,
    const float* __restrict__ bo, float* __restrict__ out,
    ushort_t* ws)
{
    __shared__ __align__(16) ushort_t smem[26112];

    const int bid = blockIdx.x;
    const int tid = threadIdx.x;

    // ws layout (no aliasing; everything written once then read):
    ushort_t* xb     = ws;                               // 4M ush
    ushort_t* Wqkvb  = ws + (size_t)XN;                  // 3M ush
    ushort_t* Wob    = ws + (size_t)XN + 3 * WN;         // 1M ush
    ushort_t* q_ws   = ws + (size_t)XN + 4 * WN;         // 4M ush each
    ushort_t* k_ws   = q_ws + (size_t)M_ * D_;
    ushort_t* v_ws   = k_ws + (size_t)M_ * D_;
    ushort_t* y_ws   = v_ws + (size_t)M_ * D_;
    float*    delta  = (float*)(y_ws + (size_t)M_ * D_); // 2M f32 (8 MB)
    ushort_t* states = (ushort_t*)(delta + (size_t)BH * NC * 4096); // 2M ush
    uint_t*   bar    = (uint_t*)(ws + ((size_t)64 << 20) / 2);      // +64 MB

    const int wave = tid >> 6;
    const int lane = tid & 63;
    const int fr   = lane & 15;
    const int quad = lane >> 4;
    const int rb   = quad * 4;

    // ---------------- stage 0: fp32 -> bf16 conversion ----------------
    {
        #pragma unroll
        for (int it = 0; it < 4; it++) {
            const int idx = bid * 512 + tid + it * 262144;
            const int e   = idx * 8;      // < 8388608
            const float* src;
            if      (e < XN)          src = x  + e;
            else if (e < XN + WN)     src = Wq + (e - XN);
            else if (e < XN + 2*WN)   src = Wk + (e - XN - WN);
            else if (e < XN + 3*WN)   src = Wv + (e - XN - 2*WN);
            else                      src = Wo + (e - XN - 3*WN);
            float4 lo = ((const float4*)src)[0];
            float4 hi = ((const float4*)src)[1];
            *(uint4*)(ws + e) = pack8(lo, hi);
        }
    }
    grid_sync_sw(bar + 0);

    // ---------------- stage 1: fused QKV projection ----------------
    // 512 tasks of 128m x 64n, all 3 z in one k-loop (A staged once).
    {
        const int r  = bid & 7;
        const int j  = bid >> 3;                    // 0..63
        const int mt = ((r >> 1) << 3) | (j & 7);   // 0..31
        const int nt = ((r & 1) << 3) | (j >> 3);   // 0..15
        const int m0 = mt * 128;
        const int n0 = nt * 64;

        ushort_t* As = smem;                        // 128*64 = 8192 ush
        ushort_t* Bs = smem + 8192;                 // 3*64*64 = 12288 ush

        const int wm = (wave >> 1) * 32;            // 4 m-waves
        const int wn = (wave & 1) * 32;             // 2 n-waves

        const ushort_t* Ag = xb + (size_t)(m0 + wave * 16) * D_;
        ushort_t* Alds = As + wave * 16 * 64;

        f32x4 acc[3][2][2];
        #pragma unroll
        for (int z = 0; z < 3; z++)
            #pragma unroll
            for (int i = 0; i < 2; i++)
                #pragma unroll
                for (int j2 = 0; j2 < 2; j2++)
                    acc[z][i][j2] = (f32x4){0.f, 0.f, 0.f, 0.f};

        for (int k0 = 0; k0 < D_; k0 += 64) {
            __syncthreads();
            stage_rows(Ag + k0, Alds, lane, 2);     // A: 16 rows/wave
            #pragma unroll
            for (int z = 0; z < 3; z++) {
                const ushort_t* Bg = Wqkvb + (size_t)z * WN
                                   + (size_t)(n0 + wave * 8) * D_;
                stage_rows(Bg + k0, Bs + z * 4096 + wave * 8 * 64, lane, 1);
            }
            __syncthreads();

            #pragma unroll
            for (int ksg = 0; ksg <= 4; ksg += 4) {
                const int kgo = ((ksg + quad) ^ (fr & 7)) << 3;
                bf16x8 af[2];
                #pragma unroll
                for (int i = 0; i < 2; i++) {
                    uint4 u = *(const uint4*)&As[(wm + i * 16 + fr) * 64 + kgo];
                    af[i] = __builtin_bit_cast(bf16x8, u);
                }
                #pragma unroll
                for (int z = 0; z < 3; z++) {
                    bf16x8 bf[2];
                    #pragma unroll
                    for (int j2 = 0; j2 < 2; j2++) {
                        uint4 u = *(const uint4*)&Bs[z * 4096 + (wn + j2 * 16 + fr) * 64 + kgo];
                        bf[j2] = __builtin_bit_cast(bf16x8, u);
                    }
                    #pragma unroll
                    for (int i = 0; i < 2; i++)
                        #pragma unroll
                        for (int j2 = 0; j2 < 2; j2++)
                            acc[z][i][j2] = __builtin_amdgcn_mfma_f32_16x16x32_bf16(
                                af[i], bf[j2], acc[z][i][j2], 0, 0, 0);
                }
            }
        }

        // epilogue: split heads, scalar bf16 stores
        #pragma unroll
        for (int z = 0; z < 3; z++) {
            const float* bi = (z == 0) ? bq : ((z == 1) ? bk : bv);
            ushort_t*    oz = (z == 0) ? q_ws : ((z == 1) ? k_ws : v_ws);
            #pragma unroll
            for (int j2 = 0; j2 < 2; j2++) {
                const int n = n0 + wn + j2 * 16 + fr;
                const float bias = bi[n];
                const int h  = n >> 6;
                const int hd = n & 63;
                #pragma unroll
                for (int i = 0; i < 2; i++) {
                    #pragma unroll
                    for (int rr = 0; rr < 4; rr++) {
                        const int m = m0 + wm + i * 16 + rb + rr;
                        const int b = m >> 11, t = m & (T_ - 1);
                        oz[(((size_t)(b * H_ + h)) * T_ + t) * HD_ + hd] =
                            f2bf(acc[z][i][j2][rr] + bias);
                    }
                }
            }
        }
    }
    grid_sync_sw(bar + 1);

    // ---------------- stage 2: per-chunk delta states ----------------
    // 512 tasks: delta[bh][c][p][n] = sum_s V[s][p]*K[s][n], fp32 out.
    {
        const int c  = bid & 15;
        const int bh = bid >> 4;
        ushort_t* VtS = smem;            // 64*136 = 8704 ush
        ushort_t* KtS = smem + 8704;     // 64*136 = 8704 ush

        const size_t base = ((size_t)bh * T_ + (size_t)c * CHK) * HD_;
        stage_T512(v_ws + base, VtS, tid);
        stage_T512(k_ws + base, KtS, tid);
        __syncthreads();

        const int p = (wave & 3) * 16 + fr;
        f32x4 accd[2];
        #pragma unroll
        for (int jj = 0; jj < 2; jj++) accd[jj] = (f32x4){0.f, 0.f, 0.f, 0.f};

        #pragma unroll
        for (int kt = 0; kt < 4; kt++) {
            const int sb   = kt * 4 + quad;
            const int blkA = (sb & 8) | ((sb ^ (p >> 3)) & 7);
            bf16x8 af = __builtin_bit_cast(bf16x8,
                *(const uint4*)&VtS[p * LDS_ + (blkA << 3)]);
            #pragma unroll
            for (int jj = 0; jj < 2; jj++) {
                const int jn   = (wave >> 2) * 2 + jj;
                const int nr   = jn * 16 + fr;
                const int blkB = (sb & 8) | ((sb ^ (nr >> 3)) & 7);
                uint4 ub = *(const uint4*)&KtS[nr * LDS_ + (blkB << 3)];
                accd[jj] = __builtin_amdgcn_mfma_f32_16x16x32_bf16(
                    af, __builtin_bit_cast(bf16x8, ub), accd[jj], 0, 0, 0);
            }
        }

        float* dp = delta + ((size_t)bh * NC + c) * 4096;
        #pragma unroll
        for (int jj = 0; jj < 2; jj++) {
            const int jn = (wave >> 2) * 2 + jj;
            #pragma unroll
            for (int r2 = 0; r2 < 4; r2++)
                dp[((wave & 3) * 16 + rb + r2) * 64 + jn * 16 + fr] = accd[jj][r2];
        }
    }
    grid_sync_sw(bar + 2);

    // ---------------- stage 3: exclusive prefix over chunks ----------------
    if (bid < 128) {
        const int bh = bid >> 2, qd = bid & 3;
        const size_t b0 = (size_t)bh * NC * 4096 + qd * 1024 + tid;
        float s0 = 0.f, s1 = 0.f;
        #pragma unroll
        for (int cc = 0; cc < NC; cc++) {
            const size_t o = b0 + (size_t)cc * 4096;
            states[o]       = f2bf(s0);  s0 += delta[o];
            states[o + 512] = f2bf(s1);  s1 += delta[o + 512];
        }
    }
    grid_sync_sw(bar + 3);

    // ---------------- stage 4: per-chunk attention ----------------
    {
        const int c = bid & 15, bh = bid >> 4;
        ushort_t* VtS  = smem;           // 8704 ush
        ushort_t* Smat = smem + 8704;    // 128*136 = 17408 ush

        const int fk = quad * 8;

        const size_t base = ((size_t)bh * T_ + (size_t)c * CHK) * HD_;
        const ushort_t* qg = q_ws + base;
        const ushort_t* kg = k_ws + base;
        const ushort_t* vg = v_ws + base;
        const ushort_t* st = states + ((size_t)bh * NC + c) * 4096;

        stage_T512(vg, VtS, tid);
        __syncthreads();

        const int m = wave;

        bf16x8 aq[2];
        #pragma unroll
        for (int kk = 0; kk < 2; kk++) {
            uint4 u = *(const uint4*)(qg + (m * 16 + fr) * HD_ + kk * 32 + fk);
            aq[kk] = __builtin_bit_cast(bf16x8, u);
        }

        f32x4 acc[4];
        #pragma unroll
        for (int jn = 0; jn < 4; jn++) acc[jn] = (f32x4){0.f, 0.f, 0.f, 0.f};

        // inter-chunk: acc += Q . S_prev^T
        #pragma unroll
        for (int jn = 0; jn < 4; jn++) {
            #pragma unroll
            for (int kk = 0; kk < 2; kk++) {
                uint4 u = *(const uint4*)(st + (jn * 16 + fr) * 64 + kk * 32 + fk);
                bf16x8 bsp = __builtin_bit_cast(bf16x8, u);
                acc[jn] = __builtin_amdgcn_mfma_f32_16x16x32_bf16(
                    aq[kk], bsp, acc[jn], 0, 0, 0);
            }
        }

        // intra-chunk: scores -> mask -> Smat -> PV
        const int nk = (m + 2) >> 1;
        const int jt = 2 * nk;

        f32x4 sc[8];
        #pragma unroll
        for (int j = 0; j < 8; j++) sc[j] = (f32x4){0.f, 0.f, 0.f, 0.f};

        #pragma unroll
        for (int j = 0; j < 8; j++) {
            if (j <= m) {
                #pragma unroll
                for (int kk = 0; kk < 2; kk++) {
                    uint4 u = *(const uint4*)(kg + (j * 16 + fr) * HD_ + kk * 32 + fk);
                    sc[j] = __builtin_amdgcn_mfma_f32_16x16x32_bf16(
                        aq[kk], __builtin_bit_cast(bf16x8, u), sc[j], 0, 0, 0);
                }
            }
        }

        #pragma unroll
        for (int j = 0; j < 8; j++) {
            if (j < jt) {
                f32x4 v = sc[j];
                if (j == m) {
                    #pragma unroll
                    for (int r2 = 0; r2 < 4; r2++)
                        if (fr > rb + r2) v[r2] = 0.f;
                }
                #pragma unroll
                for (int r2 = 0; r2 < 4; r2++)
                    Smat[(m * 16 + rb + r2) * LDS_ + j * 16 + fr] = f2bf(v[r2]);
            }
        }

        #pragma unroll
        for (int kt = 0; kt < 4; kt++) {
            if (kt < nk) {
                uint4 ua = *(const uint4*)&Smat[(m * 16 + fr) * LDS_ + kt * 32 + fk];
                bf16x8 as_ = __builtin_bit_cast(bf16x8, ua);
                #pragma unroll
                for (int jn = 0; jn < 4; jn++) {
                    const int p   = jn * 16 + fr;
                    const int sb  = kt * 4 + quad;
                    const int blk = (sb & 8) | ((sb ^ (p >> 3)) & 7);
                    uint4 ub = *(const uint4*)&VtS[p * LDS_ + (blk << 3)];
                    acc[jn] = __builtin_amdgcn_mfma_f32_16x16x32_bf16(
                        as_, __builtin_bit_cast(bf16x8, ub), acc[jn], 0, 0, 0);
                }
            }
        }

        const int b = bh >> 4, h = bh & 15;
        ushort_t* yg = y_ws + ((size_t)(b * T_ + c * CHK)) * D_ + h * 64;
        #pragma unroll
        for (int jn = 0; jn < 4; jn++) {
            #pragma unroll
            for (int r2 = 0; r2 < 4; r2++) {
                const int t = m * 16 + rb + r2;
                const int p = jn * 16 + fr;
                yg[(size_t)t * D_ + p] = f2bf(acc[jn][r2]);
            }
        }
    }
    grid_sync_sw(bar + 4);

    // ---------------- stage 5: output projection ----------------
    {
        const int r  = bid & 7;
        const int j  = bid >> 3;                       // 0..63
        const int mt = ((r >> 1) << 4) | (j & 15);     // 0..63
        const int nt = ((r & 1) << 2) | (j >> 4);      // 0..7

        ushort_t* As = smem;                           // 64*64 = 4096 ush
        ushort_t* Bs = smem + 4096;                    // 128*64 = 8192 ush

        const int m0 = mt * 64;
        const int n0 = nt * 128;
        const int wm = (wave >> 2) * 32;               // 2 m-waves
        const int wn = (wave & 3) * 32;                // 4 n-waves

        const ushort_t* Ag = y_ws + (size_t)(m0 + wave * 8) * D_;
        const ushort_t* Bg = Wob  + (size_t)(n0 + wave * 16) * D_;
        ushort_t* Alds = As + wave * 8 * 64;
        ushort_t* Blds = Bs + wave * 16 * 64;

        f32x4 acc[2][2];
        #pragma unroll
        for (int i = 0; i < 2; i++)
            #pragma unroll
            for (int j2 = 0; j2 < 2; j2++)
                acc[i][j2] = (f32x4){0.f, 0.f, 0.f, 0.f};

        for (int k0 = 0; k0 < D_; k0 += 64) {
            __syncthreads();
            stage_rows(Ag + k0, Alds, lane, 1);
            stage_rows(Bg + k0, Blds, lane, 2);
            __syncthreads();

            #pragma unroll
            for (int ksg = 0; ksg <= 4; ksg += 4) {
                const int kgo = ((ksg + quad) ^ (fr & 7)) << 3;
                bf16x8 af[2], bf[2];
                #pragma unroll
                for (int i = 0; i < 2; i++) {
                    uint4 u = *(const uint4*)&As[(wm + i * 16 + fr) * 64 + kgo];
                    af[i] = __builtin_bit_cast(bf16x8, u);
                }
                #pragma unroll
                for (int j2 = 0; j2 < 2; j2++) {
                    uint4 u = *(const uint4*)&Bs[(wn + j2 * 16 + fr) * 64 + kgo];
                    bf[j2] = __builtin_bit_cast(bf16x8, u);
                }
                #pragma unroll
                for (int i = 0; i < 2; i++)
                    #pragma unroll
                    for (int j2 = 0; j2 < 2; j2++)
                        acc[i][j2] = __builtin_amdgcn_mfma_f32_16x16x32_bf16(
                            af[i], bf[j2], acc[i][j2], 0, 0, 0);
            }
        }

        #pragma unroll
        for (int j2 = 0; j2 < 2; j2++) {
            const int n = n0 + wn + j2 * 16 + fr;
            const float bias = bo[n];
            #pragma unroll
            for (int i = 0; i < 2; i++) {
                #pragma unroll
                for (int rr = 0; rr < 4; rr++) {
                    const int m = m0 + wm + i * 16 + rb + rr;
                    out[(size_t)m * D_ + n] = acc[i][j2][rr] + bias;
                }
            }
        }
    }
}

// ---------------- launch ----------------
extern "C" void kernel_launch(void* const* d_in, const int* in_sizes, int n_in,
                              void* d_out, int out_size, void* d_ws, size_t ws_size,
                              hipStream_t stream)
{
    const float* x  = (const float*)d_in[0];
    const float* Wq = (const float*)d_in[1];
    const float* bq = (const float*)d_in[2];
    const float* Wk = (const float*)d_in[3];
    const float* bk = (const float*)d_in[4];
    const float* Wv = (const float*)d_in[5];
    const float* bv = (const float*)d_in[6];
    const float* Wo = (const float*)d_in[7];
    const float* bo = (const float*)d_in[8];
    float* out = (float*)d_out;
    ushort_t* ws = (ushort_t*)d_ws;

    // zero the 5 barrier counters (captured into the graph, replays each run)
    hipMemsetAsync((char*)d_ws + ((size_t)64 << 20), 0, 64, stream);

    fused_all<<<dim3(GRID_BLOCKS), dim3(512), 0, stream>>>(
        x, Wq, bq, Wk, bk, Wv, bv, Wo, bo, out, ws);
}

// Round 5
// 281.246 us; speedup vs baseline: 2.5540x; 2.5540x over previous
//
#include <hip/hip_runtime.h>
#include <stdint.h>

#define B_  2
#define T_  2048
#define D_  1024
#define H_  16
#define HD_ 64
#define M_  (B_*T_)      // 4096
#define CHK 128          // time chunk
#define NC  (T_/CHK)     // 16
#define BH  (B_*H_)      // 32

#define XN   4194304     // x elems (4 M)
#define WN   1048576     // one W elems (1 M)

#define GRID_BLOCKS 512

typedef unsigned short ushort_t;
typedef unsigned int   uint_t;

typedef __bf16 bf16x8 __attribute__((ext_vector_type(8)));
typedef float  f32x4  __attribute__((ext_vector_type(4)));

// ---------- bf16 helpers ----------
__device__ inline ushort_t f2bf(float f) {
    uint_t x = __float_as_uint(f);
    x += 0x7fffu + ((x >> 16) & 1u);   // RNE
    return (ushort_t)(x >> 16);
}

__device__ inline uint4 pack8(const float4& lo, const float4& hi) {
    uint4 pk;
    pk.x = (uint_t)f2bf(lo.x) | ((uint_t)f2bf(lo.y) << 16);
    pk.y = (uint_t)f2bf(lo.z) | ((uint_t)f2bf(lo.w) << 16);
    pk.z = (uint_t)f2bf(hi.x) | ((uint_t)f2bf(hi.y) << 16);
    pk.w = (uint_t)f2bf(hi.z) | ((uint_t)f2bf(hi.w) << 16);
    return pk;
}

// ---------- software grid barrier, v2: store/flag tree + RELAXED polls ----------
// R4's counter-RMW barrier spun with agent-scope ACQUIRE loads -> per-poll
// cache-invalidate storm that trashed L2 for still-running blocks (FETCH 2x
// ideal, 110us/barrier). v2: arrival = one release fence + plain flag store
// per block; block 0 aggregates with RELAXED polls (no maintenance ops);
// one go-flag release; waiters poll RELAXED, then ONE acquire fence per
// block (thread0 only — its L1-inv covers the CU; __syncthreads orders the
// rest). Epochs 1..5 monotonic; 4KB memset per launch resets.
__device__ inline void grid_sync_sw(uint_t* flags, uint_t* go, uint_t epoch) {
    __syncthreads();
    if (threadIdx.x == 0) {
        __threadfence();   // release: my block's writes -> coherence point
        __hip_atomic_store(&flags[blockIdx.x], epoch, __ATOMIC_RELAXED,
                           __HIP_MEMORY_SCOPE_AGENT);
    }
    if (blockIdx.x == 0) {
        int spins = 0;
        while (__hip_atomic_load(&flags[threadIdx.x], __ATOMIC_RELAXED,
                                 __HIP_MEMORY_SCOPE_AGENT) < epoch) {
            if (++spins > (1 << 21)) break;   // failsafe, no deadlock
            __builtin_amdgcn_s_sleep(2);
        }
        __syncthreads();                      // all 512 flags seen
        if (threadIdx.x == 0) {
            __threadfence();                  // acq_rel: pairs with both sides
            __hip_atomic_store(go, epoch, __ATOMIC_RELAXED,
                               __HIP_MEMORY_SCOPE_AGENT);
        }
    }
    if (threadIdx.x == 0) {
        int spins = 0;
        while (__hip_atomic_load(go, __ATOMIC_RELAXED,
                                 __HIP_MEMORY_SCOPE_AGENT) < epoch) {
            if (++spins > (1 << 21)) break;
            __builtin_amdgcn_s_sleep(2);
        }
        __threadfence();   // acquire: invalidate stale L1/L2 for this CU
    }
    __syncthreads();
}

// ---------------- m97-style staging: 8 rows (64 k-elems each) per issue ----------------
__device__ inline void stage_rows(const ushort_t* __restrict__ g, ushort_t* ldsw,
                                  int lane, int issues) {
    const int rr  = lane >> 3;
    const int kg8 = ((lane & 7) ^ rr) << 3;
    const ushort_t* src = g + (size_t)rr * D_ + kg8;
    #pragma unroll
    for (int i = 0; i < issues; i++) {
        __builtin_amdgcn_global_load_lds(
            (const __attribute__((address_space(1))) void*)(src + (size_t)(i * 8) * D_),
            (__attribute__((address_space(3))) void*)(ldsw + i * 512),
            16, 0, 0);
    }
}

#define LDS_ 136   // row stride (ushorts): 272 B = 68 dwords = 4-bank rotation

// swizzled transpose scatter: [128][64] bf16 tile -> dst[col p][136] with
// blk = (sb&8) | ((sb ^ (p>>3)) & 7).  512-thread version, 2 uint4/thread.
__device__ inline void stage_T512(const ushort_t* __restrict__ src, ushort_t* dst, int tid) {
    uint4 u[2];
    #pragma unroll
    for (int g = 0; g < 2; g++) u[g] = ((const uint4*)src)[tid + 512 * g];
    #pragma unroll
    for (int g = 0; g < 2; g++) {
        const int v  = tid + 512 * g;
        const int s  = v >> 3;
        const int p8 = (v & 7) * 8;
        ushort_t e[8];
        *(uint4*)e = u[g];
        const int sb = s >> 3, slo = s & 7;
        #pragma unroll
        for (int j = 0; j < 8; j++) {
            const int p   = p8 + j;
            const int blk = (sb & 8) | ((sb ^ (p >> 3)) & 7);
            dst[p * LDS_ + (blk << 3) + slo] = e[j];
        }
    }
}

// =======================================================================
// Single fused kernel: grid 512 x 512 thr, 2 blocks/CU (all co-resident).
// Stages: cvt -> gemm_qkv(z-fused) -> chunk_delta -> states_prefix ->
//         attn_chunk -> gemm_out, separated by software grid barriers.
// LDS union: max carve = 26112 ushorts (52224 B) -> 2 blocks/CU fits.
// =======================================================================
__global__ __launch_bounds__(512, 4) void fused_all(
    const float* __restrict__ x,  const float* __restrict__ Wq,
    const float* __restrict__ bq, const float* __restrict__ Wk,
    const float* __restrict__ bk, const float* __restrict__ Wv,
    const float* __restrict__ bv, const float* __restrict__ Wo,
    const float* __restrict__ bo, float* __restrict__ out,
    ushort_t* ws)
{
    __shared__ __align__(16) ushort_t smem[26112];

    const int bid = blockIdx.x;
    const int tid = threadIdx.x;

    // ws layout (no aliasing; everything written once then read):
    ushort_t* xb     = ws;                               // 4M ush
    ushort_t* Wqkvb  = ws + (size_t)XN;                  // 3M ush
    ushort_t* Wob    = ws + (size_t)XN + 3 * WN;         // 1M ush
    ushort_t* q_ws   = ws + (size_t)XN + 4 * WN;         // 4M ush each
    ushort_t* k_ws   = q_ws + (size_t)M_ * D_;
    ushort_t* v_ws   = k_ws + (size_t)M_ * D_;
    ushort_t* y_ws   = v_ws + (size_t)M_ * D_;
    float*    delta  = (float*)(y_ws + (size_t)M_ * D_); // 2M f32 (8 MB)
    ushort_t* states = (ushort_t*)(delta + (size_t)BH * NC * 4096); // 2M ush
    uint_t*   flags  = (uint_t*)(ws + ((size_t)64 << 20) / 2);      // +64 MB, 512 slots
    uint_t*   go     = flags + 512;                                  // own cacheline

    const int wave = tid >> 6;
    const int lane = tid & 63;
    const int fr   = lane & 15;
    const int quad = lane >> 4;
    const int rb   = quad * 4;

    // ---------------- stage 0: fp32 -> bf16 conversion ----------------
    {
        #pragma unroll
        for (int it = 0; it < 4; it++) {
            const int idx = bid * 512 + tid + it * 262144;
            const int e   = idx * 8;      // < 8388608
            const float* src;
            if      (e < XN)          src = x  + e;
            else if (e < XN + WN)     src = Wq + (e - XN);
            else if (e < XN + 2*WN)   src = Wk + (e - XN - WN);
            else if (e < XN + 3*WN)   src = Wv + (e - XN - 2*WN);
            else                      src = Wo + (e - XN - 3*WN);
            float4 lo = ((const float4*)src)[0];
            float4 hi = ((const float4*)src)[1];
            *(uint4*)(ws + e) = pack8(lo, hi);
        }
    }
    grid_sync_sw(flags, go, 1u);

    // ---------------- stage 1: fused QKV projection ----------------
    // 512 tasks of 128m x 64n, all 3 z in one k-loop (A staged once).
    {
        const int r  = bid & 7;
        const int j  = bid >> 3;                    // 0..63
        const int mt = ((r >> 1) << 3) | (j & 7);   // 0..31
        const int nt = ((r & 1) << 3) | (j >> 3);   // 0..15
        const int m0 = mt * 128;
        const int n0 = nt * 64;

        ushort_t* As = smem;                        // 128*64 = 8192 ush
        ushort_t* Bs = smem + 8192;                 // 3*64*64 = 12288 ush

        const int wm = (wave >> 1) * 32;            // 4 m-waves
        const int wn = (wave & 1) * 32;             // 2 n-waves

        const ushort_t* Ag = xb + (size_t)(m0 + wave * 16) * D_;
        ushort_t* Alds = As + wave * 16 * 64;

        f32x4 acc[3][2][2];
        #pragma unroll
        for (int z = 0; z < 3; z++)
            #pragma unroll
            for (int i = 0; i < 2; i++)
                #pragma unroll
                for (int j2 = 0; j2 < 2; j2++)
                    acc[z][i][j2] = (f32x4){0.f, 0.f, 0.f, 0.f};

        for (int k0 = 0; k0 < D_; k0 += 64) {
            __syncthreads();
            stage_rows(Ag + k0, Alds, lane, 2);     // A: 16 rows/wave
            #pragma unroll
            for (int z = 0; z < 3; z++) {
                const ushort_t* Bg = Wqkvb + (size_t)z * WN
                                   + (size_t)(n0 + wave * 8) * D_;
                stage_rows(Bg + k0, Bs + z * 4096 + wave * 8 * 64, lane, 1);
            }
            __syncthreads();

            #pragma unroll
            for (int ksg = 0; ksg <= 4; ksg += 4) {
                const int kgo = ((ksg + quad) ^ (fr & 7)) << 3;
                bf16x8 af[2];
                #pragma unroll
                for (int i = 0; i < 2; i++) {
                    uint4 u = *(const uint4*)&As[(wm + i * 16 + fr) * 64 + kgo];
                    af[i] = __builtin_bit_cast(bf16x8, u);
                }
                #pragma unroll
                for (int z = 0; z < 3; z++) {
                    bf16x8 bf[2];
                    #pragma unroll
                    for (int j2 = 0; j2 < 2; j2++) {
                        uint4 u = *(const uint4*)&Bs[z * 4096 + (wn + j2 * 16 + fr) * 64 + kgo];
                        bf[j2] = __builtin_bit_cast(bf16x8, u);
                    }
                    #pragma unroll
                    for (int i = 0; i < 2; i++)
                        #pragma unroll
                        for (int j2 = 0; j2 < 2; j2++)
                            acc[z][i][j2] = __builtin_amdgcn_mfma_f32_16x16x32_bf16(
                                af[i], bf[j2], acc[z][i][j2], 0, 0, 0);
                }
            }
        }

        // epilogue: split heads, scalar bf16 stores
        #pragma unroll
        for (int z = 0; z < 3; z++) {
            const float* bi = (z == 0) ? bq : ((z == 1) ? bk : bv);
            ushort_t*    oz = (z == 0) ? q_ws : ((z == 1) ? k_ws : v_ws);
            #pragma unroll
            for (int j2 = 0; j2 < 2; j2++) {
                const int n = n0 + wn + j2 * 16 + fr;
                const float bias = bi[n];
                const int h  = n >> 6;
                const int hd = n & 63;
                #pragma unroll
                for (int i = 0; i < 2; i++) {
                    #pragma unroll
                    for (int rr = 0; rr < 4; rr++) {
                        const int m = m0 + wm + i * 16 + rb + rr;
                        const int b = m >> 11, t = m & (T_ - 1);
                        oz[(((size_t)(b * H_ + h)) * T_ + t) * HD_ + hd] =
                            f2bf(acc[z][i][j2][rr] + bias);
                    }
                }
            }
        }
    }
    grid_sync_sw(flags, go, 2u);

    // ---------------- stage 2: per-chunk delta states ----------------
    // 512 tasks: delta[bh][c][p][n] = sum_s V[s][p]*K[s][n], fp32 out.
    {
        const int c  = bid & 15;
        const int bh = bid >> 4;
        ushort_t* VtS = smem;            // 64*136 = 8704 ush
        ushort_t* KtS = smem + 8704;     // 64*136 = 8704 ush

        const size_t base = ((size_t)bh * T_ + (size_t)c * CHK) * HD_;
        stage_T512(v_ws + base, VtS, tid);
        stage_T512(k_ws + base, KtS, tid);
        __syncthreads();

        const int p = (wave & 3) * 16 + fr;
        f32x4 accd[2];
        #pragma unroll
        for (int jj = 0; jj < 2; jj++) accd[jj] = (f32x4){0.f, 0.f, 0.f, 0.f};

        #pragma unroll
        for (int kt = 0; kt < 4; kt++) {
            const int sb   = kt * 4 + quad;
            const int blkA = (sb & 8) | ((sb ^ (p >> 3)) & 7);
            bf16x8 af = __builtin_bit_cast(bf16x8,
                *(const uint4*)&VtS[p * LDS_ + (blkA << 3)]);
            #pragma unroll
            for (int jj = 0; jj < 2; jj++) {
                const int jn   = (wave >> 2) * 2 + jj;
                const int nr   = jn * 16 + fr;
                const int blkB = (sb & 8) | ((sb ^ (nr >> 3)) & 7);
                uint4 ub = *(const uint4*)&KtS[nr * LDS_ + (blkB << 3)];
                accd[jj] = __builtin_amdgcn_mfma_f32_16x16x32_bf16(
                    af, __builtin_bit_cast(bf16x8, ub), accd[jj], 0, 0, 0);
            }
        }

        float* dp = delta + ((size_t)bh * NC + c) * 4096;
        #pragma unroll
        for (int jj = 0; jj < 2; jj++) {
            const int jn = (wave >> 2) * 2 + jj;
            #pragma unroll
            for (int r2 = 0; r2 < 4; r2++)
                dp[((wave & 3) * 16 + rb + r2) * 64 + jn * 16 + fr] = accd[jj][r2];
        }
    }
    grid_sync_sw(flags, go, 3u);

    // ---------------- stage 3: exclusive prefix over chunks ----------------
    if (bid < 128) {
        const int bh = bid >> 2, qd = bid & 3;
        const size_t b0 = (size_t)bh * NC * 4096 + qd * 1024 + tid;
        float s0 = 0.f, s1 = 0.f;
        #pragma unroll
        for (int cc = 0; cc < NC; cc++) {
            const size_t o = b0 + (size_t)cc * 4096;
            states[o]       = f2bf(s0);  s0 += delta[o];
            states[o + 512] = f2bf(s1);  s1 += delta[o + 512];
        }
    }
    grid_sync_sw(flags, go, 4u);

    // ---------------- stage 4: per-chunk attention ----------------
    {
        const int c = bid & 15, bh = bid >> 4;
        ushort_t* VtS  = smem;           // 8704 ush
        ushort_t* Smat = smem + 8704;    // 128*136 = 17408 ush

        const int fk = quad * 8;

        const size_t base = ((size_t)bh * T_ + (size_t)c * CHK) * HD_;
        const ushort_t* qg = q_ws + base;
        const ushort_t* kg = k_ws + base;
        const ushort_t* vg = v_ws + base;
        const ushort_t* st = states + ((size_t)bh * NC + c) * 4096;

        stage_T512(vg, VtS, tid);
        __syncthreads();

        const int m = wave;

        bf16x8 aq[2];
        #pragma unroll
        for (int kk = 0; kk < 2; kk++) {
            uint4 u = *(const uint4*)(qg + (m * 16 + fr) * HD_ + kk * 32 + fk);
            aq[kk] = __builtin_bit_cast(bf16x8, u);
        }

        f32x4 acc[4];
        #pragma unroll
        for (int jn = 0; jn < 4; jn++) acc[jn] = (f32x4){0.f, 0.f, 0.f, 0.f};

        // inter-chunk: acc += Q . S_prev^T
        #pragma unroll
        for (int jn = 0; jn < 4; jn++) {
            #pragma unroll
            for (int kk = 0; kk < 2; kk++) {
                uint4 u = *(const uint4*)(st + (jn * 16 + fr) * 64 + kk * 32 + fk);
                bf16x8 bsp = __builtin_bit_cast(bf16x8, u);
                acc[jn] = __builtin_amdgcn_mfma_f32_16x16x32_bf16(
                    aq[kk], bsp, acc[jn], 0, 0, 0);
            }
        }

        // intra-chunk: scores -> mask -> Smat -> PV
        const int nk = (m + 2) >> 1;
        const int jt = 2 * nk;

        f32x4 sc[8];
        #pragma unroll
        for (int j = 0; j < 8; j++) sc[j] = (f32x4){0.f, 0.f, 0.f, 0.f};

        #pragma unroll
        for (int j = 0; j < 8; j++) {
            if (j <= m) {
                #pragma unroll
                for (int kk = 0; kk < 2; kk++) {
                    uint4 u = *(const uint4*)(kg + (j * 16 + fr) * HD_ + kk * 32 + fk);
                    sc[j] = __builtin_amdgcn_mfma_f32_16x16x32_bf16(
                        aq[kk], __builtin_bit_cast(bf16x8, u), sc[j], 0, 0, 0);
                }
            }
        }

        #pragma unroll
        for (int j = 0; j < 8; j++) {
            if (j < jt) {
                f32x4 v = sc[j];
                if (j == m) {
                    #pragma unroll
                    for (int r2 = 0; r2 < 4; r2++)
                        if (fr > rb + r2) v[r2] = 0.f;
                }
                #pragma unroll
                for (int r2 = 0; r2 < 4; r2++)
                    Smat[(m * 16 + rb + r2) * LDS_ + j * 16 + fr] = f2bf(v[r2]);
            }
        }

        #pragma unroll
        for (int kt = 0; kt < 4; kt++) {
            if (kt < nk) {
                uint4 ua = *(const uint4*)&Smat[(m * 16 + fr) * LDS_ + kt * 32 + fk];
                bf16x8 as_ = __builtin_bit_cast(bf16x8, ua);
                #pragma unroll
                for (int jn = 0; jn < 4; jn++) {
                    const int p   = jn * 16 + fr;
                    const int sb  = kt * 4 + quad;
                    const int blk = (sb & 8) | ((sb ^ (p >> 3)) & 7);
                    uint4 ub = *(const uint4*)&VtS[p * LDS_ + (blk << 3)];
                    acc[jn] = __builtin_amdgcn_mfma_f32_16x16x32_bf16(
                        as_, __builtin_bit_cast(bf16x8, ub), acc[jn], 0, 0, 0);
                }
            }
        }

        const int b = bh >> 4, h = bh & 15;
        ushort_t* yg = y_ws + ((size_t)(b * T_ + c * CHK)) * D_ + h * 64;
        #pragma unroll
        for (int jn = 0; jn < 4; jn++) {
            #pragma unroll
            for (int r2 = 0; r2 < 4; r2++) {
                const int t = m * 16 + rb + r2;
                const int p = jn * 16 + fr;
                yg[(size_t)t * D_ + p] = f2bf(acc[jn][r2]);
            }
        }
    }
    grid_sync_sw(flags, go, 5u);

    // ---------------- stage 5: output projection ----------------
    {
        const int r  = bid & 7;
        const int j  = bid >> 3;                       // 0..63
        const int mt = ((r >> 1) << 4) | (j & 15);     // 0..63
        const int nt = ((r & 1) << 2) | (j >> 4);      // 0..7

        ushort_t* As = smem;                           // 64*64 = 4096 ush
        ushort_t* Bs = smem + 4096;                    // 128*64 = 8192 ush

        const int m0 = mt * 64;
        const int n0 = nt * 128;
        const int wm = (wave >> 2) * 32;               // 2 m-waves
        const int wn = (wave & 3) * 32;                // 4 n-waves

        const ushort_t* Ag = y_ws + (size_t)(m0 + wave * 8) * D_;
        const ushort_t* Bg = Wob  + (size_t)(n0 + wave * 16) * D_;
        ushort_t* Alds = As + wave * 8 * 64;
        ushort_t* Blds = Bs + wave * 16 * 64;

        f32x4 acc[2][2];
        #pragma unroll
        for (int i = 0; i < 2; i++)
            #pragma unroll
            for (int j2 = 0; j2 < 2; j2++)
                acc[i][j2] = (f32x4){0.f, 0.f, 0.f, 0.f};

        for (int k0 = 0; k0 < D_; k0 += 64) {
            __syncthreads();
            stage_rows(Ag + k0, Alds, lane, 1);
            stage_rows(Bg + k0, Blds, lane, 2);
            __syncthreads();

            #pragma unroll
            for (int ksg = 0; ksg <= 4; ksg += 4) {
                const int kgo = ((ksg + quad) ^ (fr & 7)) << 3;
                bf16x8 af[2], bf[2];
                #pragma unroll
                for (int i = 0; i < 2; i++) {
                    uint4 u = *(const uint4*)&As[(wm + i * 16 + fr) * 64 + kgo];
                    af[i] = __builtin_bit_cast(bf16x8, u);
                }
                #pragma unroll
                for (int j2 = 0; j2 < 2; j2++) {
                    uint4 u = *(const uint4*)&Bs[(wn + j2 * 16 + fr) * 64 + kgo];
                    bf[j2] = __builtin_bit_cast(bf16x8, u);
                }
                #pragma unroll
                for (int i = 0; i < 2; i++)
                    #pragma unroll
                    for (int j2 = 0; j2 < 2; j2++)
                        acc[i][j2] = __builtin_amdgcn_mfma_f32_16x16x32_bf16(
                            af[i], bf[j2], acc[i][j2], 0, 0, 0);
            }
        }

        #pragma unroll
        for (int j2 = 0; j2 < 2; j2++) {
            const int n = n0 + wn + j2 * 16 + fr;
            const float bias = bo[n];
            #pragma unroll
            for (int i = 0; i < 2; i++) {
                #pragma unroll
                for (int rr = 0; rr < 4; rr++) {
                    const int m = m0 + wm + i * 16 + rb + rr;
                    out[(size_t)m * D_ + n] = acc[i][j2][rr] + bias;
                }
            }
        }
    }
}

// ---------------- launch ----------------
extern "C" void kernel_launch(void* const* d_in, const int* in_sizes, int n_in,
                              void* d_out, int out_size, void* d_ws, size_t ws_size,
                              hipStream_t stream)
{
    const float* x  = (const float*)d_in[0];
    const float* Wq = (const float*)d_in[1];
    const float* bq = (const float*)d_in[2];
    const float* Wk = (const float*)d_in[3];
    const float* bk = (const float*)d_in[4];
    const float* Wv = (const float*)d_in[5];
    const float* bv = (const float*)d_in[6];
    const float* Wo = (const float*)d_in[7];
    const float* bo = (const float*)d_in[8];
    float* out = (float*)d_out;
    ushort_t* ws = (ushort_t*)d_ws;

    // zero flags[512] + go (captured into the graph, replays each run)
    hipMemsetAsync((char*)d_ws + ((size_t)64 << 20), 0, 4096, stream);

    fused_all<<<dim3(GRID_BLOCKS), dim3(512), 0, stream>>>(
        x, Wq, bq, Wk, bk, Wv, bv, Wo, bo, out, ws);
}

// Round 6
// 167.378 us; speedup vs baseline: 4.2914x; 1.6803x over previous
//
#include <hip/hip_runtime.h>
#include <stdint.h>

#define B_  2
#define T_  2048
#define D_  1024
#define H_  16
#define HD_ 64
#define M_  (B_*T_)      // 4096
#define CHK 128          // time chunk
#define NC  (T_/CHK)     // 16
#define BH  (B_*H_)      // 32

#define XN   4194304     // x elems (4 M)
#define WN   1048576     // one W elems (1 M)

typedef unsigned short ushort_t;
typedef unsigned int   uint_t;

typedef __bf16 bf16x8 __attribute__((ext_vector_type(8)));
typedef float  f32x4  __attribute__((ext_vector_type(4)));

// ---------- bf16 helpers ----------
__device__ inline ushort_t f2bf(float f) {
    uint_t x = __float_as_uint(f);
    x += 0x7fffu + ((x >> 16) & 1u);   // RNE
    return (ushort_t)(x >> 16);
}

__device__ inline uint4 pack8(const float4& lo, const float4& hi) {
    uint4 pk;
    pk.x = (uint_t)f2bf(lo.x) | ((uint_t)f2bf(lo.y) << 16);
    pk.y = (uint_t)f2bf(lo.z) | ((uint_t)f2bf(lo.w) << 16);
    pk.z = (uint_t)f2bf(hi.x) | ((uint_t)f2bf(hi.y) << 16);
    pk.w = (uint_t)f2bf(hi.z) | ((uint_t)f2bf(hi.w) << 16);
    return pk;
}

// ---------------- fp32 -> bf16 pre-conversion (one contiguous dest) ----------------
__global__ __launch_bounds__(256) void to_bf16_all(
    const float* __restrict__ x,  const float* __restrict__ Wq,
    const float* __restrict__ Wk, const float* __restrict__ Wv,
    const float* __restrict__ Wo, ushort_t* __restrict__ dst)
{
    const int idx = blockIdx.x * 256 + threadIdx.x;
    const int e   = idx * 8;
    const float* src;
    if      (e < XN)          src = x  + e;
    else if (e < XN + WN)     src = Wq + (e - XN);
    else if (e < XN + 2*WN)   src = Wk + (e - XN - WN);
    else if (e < XN + 3*WN)   src = Wv + (e - XN - 2*WN);
    else                      src = Wo + (e - XN - 3*WN);
    float4 lo = ((const float4*)src)[0];
    float4 hi = ((const float4*)src)[1];
    *(uint4*)(dst + e) = pack8(lo, hi);
}

// ---------------- m97-style bf16 GEMM core pieces ----------------
__device__ inline void stage_rows(const ushort_t* __restrict__ g, ushort_t* ldsw,
                                  int lane, int issues) {
    const int rr  = lane >> 3;
    const int kg8 = ((lane & 7) ^ rr) << 3;
    const ushort_t* src = g + (size_t)rr * D_ + kg8;
    #pragma unroll
    for (int i = 0; i < issues; i++) {
        __builtin_amdgcn_global_load_lds(
            (const __attribute__((address_space(1))) void*)(src + (size_t)(i * 8) * D_),
            (__attribute__((address_space(3))) void*)(ldsw + i * 512),
            16, 0, 0);
    }
}

// Fused QKV projection. Tile 64m x 128n -> 1536 blocks = 6 blocks/CU
// (R1-proven config, 162.4us end-to-end). XCD rectangle decode.
__global__ __launch_bounds__(256) void gemm_qkv(
    const ushort_t* __restrict__ xb, const ushort_t* __restrict__ Wqkvb,
    const float* __restrict__ bq, const float* __restrict__ bk,
    const float* __restrict__ bv, ushort_t* __restrict__ qkv_ws)
{
    const int flat = blockIdx.x;          // 0..1535
    const int r    = flat & 7;            // XCD (assumed flat%8 placement)
    const int j    = flat >> 3;           // 0..191
    const int mt   = ((r >> 1) << 4) | (j & 15);        // m-tile 0..63
    const int nt   = ((r & 1) << 2) | ((j >> 4) & 3);   // n-tile 0..7
    const int z    = j >> 6;                            // 0..2

    const ushort_t* W  = Wqkvb + (size_t)z * WN;
    const float*    bi = (z == 0) ? bq : ((z == 1) ? bk : bv);
    ushort_t* out = qkv_ws + (size_t)z * (size_t)M_ * D_;

    __shared__ __align__(16) ushort_t As[64 * 64];    // 8 KB
    __shared__ __align__(16) ushort_t Bs[128 * 64];   // 16 KB

    const int tid  = threadIdx.x;
    const int m0   = mt * 64;
    const int n0   = nt * 128;
    const int wave = tid >> 6;
    const int lane = tid & 63;
    const int wm   = (wave >> 1) * 32;
    const int wn   = (wave & 1) * 64;
    const int fr   = lane & 15;
    const int quad = lane >> 4;

    const ushort_t* Ag = xb + (size_t)(m0 + wave * 16) * D_;
    const ushort_t* Bg = W  + (size_t)(n0 + wave * 32) * D_;
    ushort_t* Alds = &As[wave * 16 * 64];
    ushort_t* Blds = &Bs[wave * 32 * 64];

    f32x4 acc[2][4];
    #pragma unroll
    for (int i = 0; i < 2; i++)
        #pragma unroll
        for (int j2 = 0; j2 < 4; j2++)
            acc[i][j2] = (f32x4){0.f, 0.f, 0.f, 0.f};

    for (int k0 = 0; k0 < D_; k0 += 64) {
        __syncthreads();
        stage_rows(Ag + k0, Alds, lane, 2);   // A: 16 rows/wave
        stage_rows(Bg + k0, Blds, lane, 4);   // B: 32 rows/wave
        __syncthreads();

        #pragma unroll
        for (int ksg = 0; ksg <= 4; ksg += 4) {
            const int kgo = ((ksg + quad) ^ (fr & 7)) << 3;
            bf16x8 af[2], bf[4];
            #pragma unroll
            for (int i = 0; i < 2; i++) {
                uint4 u = *(const uint4*)&As[(wm + i * 16 + fr) * 64 + kgo];
                af[i] = __builtin_bit_cast(bf16x8, u);
            }
            #pragma unroll
            for (int j2 = 0; j2 < 4; j2++) {
                uint4 u = *(const uint4*)&Bs[(wn + j2 * 16 + fr) * 64 + kgo];
                bf[j2] = __builtin_bit_cast(bf16x8, u);
            }
            #pragma unroll
            for (int i = 0; i < 2; i++)
                #pragma unroll
                for (int j2 = 0; j2 < 4; j2++)
                    acc[i][j2] = __builtin_amdgcn_mfma_f32_16x16x32_bf16(
                        af[i], bf[j2], acc[i][j2], 0, 0, 0);
        }
    }

    // epilogue: split heads, scalar stores
    const int rb = quad * 4;
    #pragma unroll
    for (int j2 = 0; j2 < 4; j2++) {
        const int n = n0 + wn + j2 * 16 + fr;
        const float bias = bi[n];
        const int h  = n >> 6;
        const int hd = n & 63;
        #pragma unroll
        for (int i = 0; i < 2; i++) {
            #pragma unroll
            for (int rr = 0; rr < 4; rr++) {
                const int m = m0 + wm + i * 16 + rb + rr;
                const int b = m >> 11, t = m & (T_ - 1);
                out[(((size_t)(b * H_ + h)) * T_ + t) * HD_ + hd] =
                    f2bf(acc[i][j2][rr] + bias);
            }
        }
    }
}

// Output projection (R1-proven config: 64x128 tile, 256 thr, grid 512).
__global__ __launch_bounds__(256) void gemm_out(
    const ushort_t* __restrict__ Yw, const ushort_t* __restrict__ Wob,
    const float* __restrict__ bo, float* __restrict__ out)
{
    const int flat = blockIdx.x;          // 0..511
    const int r    = flat & 7;
    const int j    = flat >> 3;           // 0..63
    const int mt   = ((r >> 1) << 4) | (j & 15);   // 0..63
    const int nt   = ((r & 1) << 2) | (j >> 4);    // 0..7

    __shared__ __align__(16) ushort_t As[64 * 64];
    __shared__ __align__(16) ushort_t Bs[128 * 64];

    const int tid  = threadIdx.x;
    const int m0   = mt * 64;
    const int n0   = nt * 128;
    const int wave = tid >> 6;
    const int lane = tid & 63;
    const int wm   = (wave >> 1) * 32;
    const int wn   = (wave & 1) * 64;
    const int fr   = lane & 15;
    const int quad = lane >> 4;

    const ushort_t* Ag = Yw  + (size_t)(m0 + wave * 16) * D_;
    const ushort_t* Bg = Wob + (size_t)(n0 + wave * 32) * D_;
    ushort_t* Alds = &As[wave * 16 * 64];
    ushort_t* Blds = &Bs[wave * 32 * 64];

    f32x4 acc[2][4];
    #pragma unroll
    for (int i = 0; i < 2; i++)
        #pragma unroll
        for (int j2 = 0; j2 < 4; j2++)
            acc[i][j2] = (f32x4){0.f, 0.f, 0.f, 0.f};

    for (int k0 = 0; k0 < D_; k0 += 64) {
        __syncthreads();
        stage_rows(Ag + k0, Alds, lane, 2);
        stage_rows(Bg + k0, Blds, lane, 4);
        __syncthreads();

        #pragma unroll
        for (int ksg = 0; ksg <= 4; ksg += 4) {
            const int kgo = ((ksg + quad) ^ (fr & 7)) << 3;
            bf16x8 af[2], bf[4];
            #pragma unroll
            for (int i = 0; i < 2; i++) {
                uint4 u = *(const uint4*)&As[(wm + i * 16 + fr) * 64 + kgo];
                af[i] = __builtin_bit_cast(bf16x8, u);
            }
            #pragma unroll
            for (int j2 = 0; j2 < 4; j2++) {
                uint4 u = *(const uint4*)&Bs[(wn + j2 * 16 + fr) * 64 + kgo];
                bf[j2] = __builtin_bit_cast(bf16x8, u);
            }
            #pragma unroll
            for (int i = 0; i < 2; i++)
                #pragma unroll
                for (int j2 = 0; j2 < 4; j2++)
                    acc[i][j2] = __builtin_amdgcn_mfma_f32_16x16x32_bf16(
                        af[i], bf[j2], acc[i][j2], 0, 0, 0);
        }
    }

    const int rb = quad * 4;
    #pragma unroll
    for (int j2 = 0; j2 < 4; j2++) {
        const int n = n0 + wn + j2 * 16 + fr;
        const float bias = bo[n];
        #pragma unroll
        for (int i = 0; i < 2; i++) {
            #pragma unroll
            for (int rr = 0; rr < 4; rr++) {
                const int m = m0 + wm + i * 16 + rb + rr;
                out[(size_t)m * D_ + n] = acc[i][j2][rr] + bias;
            }
        }
    }
}

#define LDS_ 136   // row stride (ushorts): 272 B = 68 dwords = 4-bank rotation

// swizzled transpose scatter from registers: uint4 g of [128][64] tile ->
// dst[row][blk*8 + s&7], blk = (sb&8) | ((sb ^ (row>>3)) & 7).  (proven)
__device__ inline void scatter_T(const uint4* u, ushort_t* dst, int tid) {
    #pragma unroll
    for (int g = 0; g < 4; g++) {
        const int v  = tid + 256 * g;
        const int s  = v >> 3;
        const int p8 = (v & 7) * 8;
        ushort_t e[8];
        *(uint4*)e = u[g];
        const int sb = s >> 3, slo = s & 7;
        #pragma unroll
        for (int j = 0; j < 8; j++) {
            const int p   = p8 + j;
            const int blk = (sb & 8) | ((sb ^ (p >> 3)) & 7);
            dst[p * LDS_ + (blk << 3) + slo] = e[j];
        }
    }
}

__device__ inline void stage_T(const ushort_t* __restrict__ src, ushort_t* dst, int tid) {
    uint4 u[4];
    #pragma unroll
    for (int g = 0; g < 4; g++) u[g] = ((const uint4*)src)[tid + 256 * g];
    scatter_T(u, dst, tid);
}

// 512-thread variant of stage_T (same swizzle, 2 groups of 512 uint4)
__device__ inline void stage_T512(const ushort_t* __restrict__ src, ushort_t* dst, int tid) {
    uint4 u[2];
    #pragma unroll
    for (int g = 0; g < 2; g++) u[g] = ((const uint4*)src)[tid + 512 * g];
    #pragma unroll
    for (int g = 0; g < 2; g++) {
        const int v  = tid + 512 * g;
        const int s  = v >> 3;
        const int p8 = (v & 7) * 8;
        ushort_t e[8];
        *(uint4*)e = u[g];
        const int sb = s >> 3, slo = s & 7;
        #pragma unroll
        for (int j = 0; j < 8; j++) {
            const int p   = p8 + j;
            const int blk = (sb & 8) | ((sb ^ (p >> 3)) & 7);
            dst[p * LDS_ + (blk << 3) + slo] = e[j];
        }
    }
}

// ---------------- per-chunk delta states (fully parallel over chunks) ----------------
// delta[bh][c][p][n] = sum_s V[s][p] * K[s][n]  (64x64, K-dim s=128), fp32 out.
__global__ __launch_bounds__(256) void chunk_delta(
    const ushort_t* __restrict__ k_ws, const ushort_t* __restrict__ v_ws,
    float* __restrict__ delta)
{
    const int c  = blockIdx.x;          // 0..15
    const int bh = blockIdx.y;          // 0..31
    __shared__ __align__(16) ushort_t VtS[64 * LDS_];   // V^T [p][s] swizzled
    __shared__ __align__(16) ushort_t KtS[64 * LDS_];   // K^T [n][s] swizzled

    const int tid  = threadIdx.x;
    const int wave = tid >> 6, lane = tid & 63;
    const int fr = lane & 15, quad = lane >> 4, rb = quad * 4;
    const int p  = wave * 16 + fr;

    const size_t base = ((size_t)bh * T_ + (size_t)c * CHK) * HD_;
    stage_T(v_ws + base, VtS, tid);
    stage_T(k_ws + base, KtS, tid);
    __syncthreads();

    f32x4 acc[4];
    #pragma unroll
    for (int jn = 0; jn < 4; jn++) acc[jn] = (f32x4){0.f, 0.f, 0.f, 0.f};

    #pragma unroll
    for (int kt = 0; kt < 4; kt++) {
        const int sb   = kt * 4 + quad;
        const int blkA = (sb & 8) | ((sb ^ (p >> 3)) & 7);
        bf16x8 af = __builtin_bit_cast(bf16x8,
            *(const uint4*)&VtS[p * LDS_ + (blkA << 3)]);
        #pragma unroll
        for (int jn = 0; jn < 4; jn++) {
            const int nr   = jn * 16 + fr;
            const int blkB = (sb & 8) | ((sb ^ (nr >> 3)) & 7);
            uint4 ub = *(const uint4*)&KtS[nr * LDS_ + (blkB << 3)];
            acc[jn] = __builtin_amdgcn_mfma_f32_16x16x32_bf16(
                af, __builtin_bit_cast(bf16x8, ub), acc[jn], 0, 0, 0);
        }
    }

    float* dp = delta + ((size_t)bh * NC + c) * 4096;
    #pragma unroll
    for (int jn = 0; jn < 4; jn++)
        #pragma unroll
        for (int r = 0; r < 4; r++)
            dp[(wave * 16 + rb + r) * 64 + jn * 16 + fr] = acc[jn][r];
}

// ---------------- per-chunk attention (512 thr) + in-block state prefix ----------------
// Replaces the separate states_prefix kernel: each block sums delta[bh][0..c-1]
// (fp32, chunk-ascending = bit-identical to the old prefix kernel), rounds to
// bf16 once, and serves the state tile from LDS. Removes 1 kernel + 1 boundary
// + the 4 MB states round-trip; costs avg 8x16KB LLC-resident reads per block.
#define STS_ 72    // state tile row stride (ush): 144 B = 36 dwords -> 4-bank rot
__global__ __launch_bounds__(512) void attn_chunk(
    const ushort_t* __restrict__ q_ws, const ushort_t* __restrict__ k_ws,
    const ushort_t* __restrict__ v_ws, const float* __restrict__ delta,
    ushort_t* __restrict__ y_ws)
{
    const int c = blockIdx.x, bh = blockIdx.y;
    __shared__ __align__(16) ushort_t VtS[64 * LDS_];    // V^T [p][s] swizzled
    __shared__ __align__(16) ushort_t Smat[128 * LDS_];  // masked scores [t][s]
    __shared__ __align__(16) ushort_t StS[64 * STS_];    // state S_prev [p][n] bf16

    const int tid  = threadIdx.x;
    const int wave = tid >> 6;        // 0..7 = m-tile
    const int lane = tid & 63;
    const int fr   = lane & 15;
    const int quad = lane >> 4;
    const int fk   = quad * 8;
    const int rb   = quad * 4;

    const size_t base = ((size_t)bh * T_ + (size_t)c * CHK) * HD_;
    const ushort_t* qg = q_ws + base;
    const ushort_t* kg = k_ws + base;
    const ushort_t* vg = v_ws + base;

    stage_T512(vg, VtS, tid);

    // in-block exclusive prefix: sum delta[bh][cc], cc < c (8 f32/thread)
    if (c > 0) {
        float s[8];
        #pragma unroll
        for (int i = 0; i < 8; i++) s[i] = 0.f;
        const float* dbase = delta + (size_t)bh * NC * 4096 + tid * 8;
        for (int cc = 0; cc < c; cc++) {
            const float* dp = dbase + (size_t)cc * 4096;
            float4 a = ((const float4*)dp)[0];
            float4 b = ((const float4*)dp)[1];
            s[0] += a.x; s[1] += a.y; s[2] += a.z; s[3] += a.w;
            s[4] += b.x; s[5] += b.y; s[6] += b.z; s[7] += b.w;
        }
        ushort_t ev[8];
        #pragma unroll
        for (int i = 0; i < 8; i++) ev[i] = f2bf(s[i]);
        // elem e = tid*8+i -> row p = e>>6 = tid>>3, col n = (tid&7)*8 + i
        *(uint4*)&StS[(tid >> 3) * STS_ + (tid & 7) * 8] = *(uint4*)ev;
    }
    __syncthreads();

    const int m = wave;

    bf16x8 aq[2];
    #pragma unroll
    for (int kk = 0; kk < 2; kk++) {
        uint4 u = *(const uint4*)(qg + (m * 16 + fr) * HD_ + kk * 32 + fk);
        aq[kk] = __builtin_bit_cast(bf16x8, u);
    }

    f32x4 acc[4];
    #pragma unroll
    for (int jn = 0; jn < 4; jn++) acc[jn] = (f32x4){0.f, 0.f, 0.f, 0.f};

    // inter-chunk: acc += Q . S_prev^T (bf16 state tile from LDS)
    if (c > 0) {
        #pragma unroll
        for (int jn = 0; jn < 4; jn++) {
            #pragma unroll
            for (int kk = 0; kk < 2; kk++) {
                uint4 u = *(const uint4*)&StS[(jn * 16 + fr) * STS_ + kk * 32 + fk];
                bf16x8 bsp = __builtin_bit_cast(bf16x8, u);
                acc[jn] = __builtin_amdgcn_mfma_f32_16x16x32_bf16(
                    aq[kk], bsp, acc[jn], 0, 0, 0);
            }
        }
    }

    // intra-chunk: scores -> mask -> Smat -> PV
    const int nk = (m + 2) >> 1;
    const int jt = 2 * nk;

    f32x4 sc[8];
    #pragma unroll
    for (int j = 0; j < 8; j++) sc[j] = (f32x4){0.f, 0.f, 0.f, 0.f};

    #pragma unroll
    for (int j = 0; j < 8; j++) {
        if (j <= m) {
            #pragma unroll
            for (int kk = 0; kk < 2; kk++) {
                uint4 u = *(const uint4*)(kg + (j * 16 + fr) * HD_ + kk * 32 + fk);
                sc[j] = __builtin_amdgcn_mfma_f32_16x16x32_bf16(
                    aq[kk], __builtin_bit_cast(bf16x8, u), sc[j], 0, 0, 0);
            }
        }
    }

    #pragma unroll
    for (int j = 0; j < 8; j++) {
        if (j < jt) {
            f32x4 v = sc[j];
            if (j == m) {
                #pragma unroll
                for (int r = 0; r < 4; r++)
                    if (fr > rb + r) v[r] = 0.f;
            }
            #pragma unroll
            for (int r = 0; r < 4; r++)
                Smat[(m * 16 + rb + r) * LDS_ + j * 16 + fr] = f2bf(v[r]);
        }
    }

    #pragma unroll
    for (int kt = 0; kt < 4; kt++) {
        if (kt < nk) {
            uint4 ua = *(const uint4*)&Smat[(m * 16 + fr) * LDS_ + kt * 32 + fk];
            bf16x8 as_ = __builtin_bit_cast(bf16x8, ua);
            #pragma unroll
            for (int jn = 0; jn < 4; jn++) {
                const int p   = jn * 16 + fr;
                const int sb  = kt * 4 + quad;
                const int blk = (sb & 8) | ((sb ^ (p >> 3)) & 7);
                uint4 ub = *(const uint4*)&VtS[p * LDS_ + (blk << 3)];
                acc[jn] = __builtin_amdgcn_mfma_f32_16x16x32_bf16(
                    as_, __builtin_bit_cast(bf16x8, ub), acc[jn], 0, 0, 0);
            }
        }
    }

    const int b = bh >> 4, h = bh & 15;
    ushort_t* yg = y_ws + ((size_t)(b * T_ + c * CHK)) * D_ + h * 64;
    #pragma unroll
    for (int jn = 0; jn < 4; jn++) {
        #pragma unroll
        for (int r = 0; r < 4; r++) {
            const int t = m * 16 + rb + r;
            const int p = jn * 16 + fr;
            yg[(size_t)t * D_ + p] = f2bf(acc[jn][r]);
        }
    }
}

// ---------------- launch ----------------
extern "C" void kernel_launch(void* const* d_in, const int* in_sizes, int n_in,
                              void* d_out, int out_size, void* d_ws, size_t ws_size,
                              hipStream_t stream)
{
    const float* x  = (const float*)d_in[0];
    const float* Wq = (const float*)d_in[1];
    const float* bq = (const float*)d_in[2];
    const float* Wk = (const float*)d_in[3];
    const float* bk = (const float*)d_in[4];
    const float* Wv = (const float*)d_in[5];
    const float* bv = (const float*)d_in[6];
    const float* Wo = (const float*)d_in[7];
    const float* bo = (const float*)d_in[8];
    float* out = (float*)d_out;

    // ws layout (ushort elems): [xb 4M][Wqb 1M][Wkb 1M][Wvb 1M][Wob 1M][q 4M][k 4M][v 4M][y 4M]
    // = 48 MB, then delta fp32 8 MB at +48 MB.
    ushort_t* cvt    = (ushort_t*)d_ws;
    ushort_t* xb     = cvt;
    ushort_t* Wqkvb  = cvt + (size_t)XN;
    ushort_t* Wob    = cvt + (size_t)XN + 3 * WN;
    ushort_t* q_ws   = cvt + (size_t)XN + 4 * WN;
    ushort_t* k_ws   = q_ws + (size_t)M_ * D_;
    ushort_t* v_ws   = k_ws + (size_t)M_ * D_;
    ushort_t* y_ws   = v_ws + (size_t)M_ * D_;
    float*    delta  = (float*)(y_ws + (size_t)M_ * D_);  // +48 MB, 8 MB fp32

    to_bf16_all<<<dim3((XN + 4 * WN) / 8 / 256), 256, 0, stream>>>(
        x, Wq, Wk, Wv, Wo, cvt);
    gemm_qkv<<<dim3(1536), 256, 0, stream>>>(
        xb, Wqkvb, bq, bk, bv, q_ws);
    chunk_delta<<<dim3(NC, BH), 256, 0, stream>>>(k_ws, v_ws, delta);
    attn_chunk<<<dim3(NC, BH), 512, 0, stream>>>(q_ws, k_ws, v_ws, delta, y_ws);
    gemm_out<<<dim3(512), 256, 0, stream>>>(y_ws, Wob, bo, out);
}

// Round 7
// 161.874 us; speedup vs baseline: 4.4373x; 1.0340x over previous
//
#include <hip/hip_runtime.h>
#include <stdint.h>

#define B_  2
#define T_  2048
#define D_  1024
#define H_  16
#define HD_ 64
#define M_  (B_*T_)      // 4096
#define CHK 128          // time chunk
#define NC  (T_/CHK)     // 16
#define BH  (B_*H_)      // 32

#define XN   4194304     // x elems (4 M)
#define WN   1048576     // one W elems (1 M)

typedef unsigned short ushort_t;
typedef unsigned int   uint_t;

typedef __bf16 bf16x8 __attribute__((ext_vector_type(8)));
typedef float  f32x4  __attribute__((ext_vector_type(4)));

// ---------- bf16 helpers ----------
__device__ inline ushort_t f2bf(float f) {
    uint_t x = __float_as_uint(f);
    x += 0x7fffu + ((x >> 16) & 1u);   // RNE
    return (ushort_t)(x >> 16);
}

__device__ inline uint4 pack8(const float4& lo, const float4& hi) {
    uint4 pk;
    pk.x = (uint_t)f2bf(lo.x) | ((uint_t)f2bf(lo.y) << 16);
    pk.y = (uint_t)f2bf(lo.z) | ((uint_t)f2bf(lo.w) << 16);
    pk.z = (uint_t)f2bf(hi.x) | ((uint_t)f2bf(hi.y) << 16);
    pk.w = (uint_t)f2bf(hi.z) | ((uint_t)f2bf(hi.w) << 16);
    return pk;
}

// ---------------- fp32 -> bf16 pre-conversion (one contiguous dest) ----------------
__global__ __launch_bounds__(256) void to_bf16_all(
    const float* __restrict__ x,  const float* __restrict__ Wq,
    const float* __restrict__ Wk, const float* __restrict__ Wv,
    const float* __restrict__ Wo, ushort_t* __restrict__ dst)
{
    const int idx = blockIdx.x * 256 + threadIdx.x;
    const int e   = idx * 8;
    const float* src;
    if      (e < XN)          src = x  + e;
    else if (e < XN + WN)     src = Wq + (e - XN);
    else if (e < XN + 2*WN)   src = Wk + (e - XN - WN);
    else if (e < XN + 3*WN)   src = Wv + (e - XN - 2*WN);
    else                      src = Wo + (e - XN - 3*WN);
    float4 lo = ((const float4*)src)[0];
    float4 hi = ((const float4*)src)[1];
    *(uint4*)(dst + e) = pack8(lo, hi);
}

// ---------------- m97-style bf16 GEMM core pieces ----------------
__device__ inline void stage_rows(const ushort_t* __restrict__ g, ushort_t* ldsw,
                                  int lane, int issues) {
    const int rr  = lane >> 3;
    const int kg8 = ((lane & 7) ^ rr) << 3;
    const ushort_t* src = g + (size_t)rr * D_ + kg8;
    #pragma unroll
    for (int i = 0; i < issues; i++) {
        __builtin_amdgcn_global_load_lds(
            (const __attribute__((address_space(1))) void*)(src + (size_t)(i * 8) * D_),
            (__attribute__((address_space(3))) void*)(ldsw + i * 512),
            16, 0, 0);
    }
}

// Fused QKV projection, z-fused: 512 blocks x 512 thr (2/CU, 16 waves/CU).
// One block = 128m x 64n for ALL of Q,K,V in a single k-loop: A staged once
// for 3 outputs. Staged traffic 576 -> 320 MB vs the 64x128-per-z config;
// MFMA:ds_read 24:8 vs 16:6 per wave-iter. Body = R4/R5 fused stage 1
// (correctness proven at absmax 2.0). XCD rectangle: XCD r owns 8 mt x 8 nt.
__global__ __launch_bounds__(512) void gemm_qkv(
    const ushort_t* __restrict__ xb, const ushort_t* __restrict__ Wqkvb,
    const float* __restrict__ bq, const float* __restrict__ bk,
    const float* __restrict__ bv, ushort_t* __restrict__ qkv_ws)
{
    const int bid = blockIdx.x;                 // 0..511
    const int r   = bid & 7;                    // XCD (assumed flat%8 placement)
    const int j   = bid >> 3;                   // 0..63
    const int mt  = ((r >> 1) << 3) | (j & 7);  // m-tile 0..31
    const int nt  = ((r & 1) << 3) | (j >> 3);  // n-tile 0..15
    const int m0  = mt * 128;
    const int n0  = nt * 64;

    __shared__ __align__(16) ushort_t As[128 * 64];      // 16 KB
    __shared__ __align__(16) ushort_t Bs[3 * 64 * 64];   // 24 KB

    const int tid  = threadIdx.x;
    const int wave = tid >> 6;            // 0..7
    const int lane = tid & 63;
    const int wm   = (wave >> 1) * 32;    // 4 m-wave-pairs
    const int wn   = (wave & 1) * 32;     // 2 n-halves
    const int fr   = lane & 15;
    const int quad = lane >> 4;
    const int rb   = quad * 4;

    const ushort_t* Ag = xb + (size_t)(m0 + wave * 16) * D_;
    ushort_t* Alds = &As[wave * 16 * 64];

    f32x4 acc[3][2][2];
    #pragma unroll
    for (int z = 0; z < 3; z++)
        #pragma unroll
        for (int i = 0; i < 2; i++)
            #pragma unroll
            for (int j2 = 0; j2 < 2; j2++)
                acc[z][i][j2] = (f32x4){0.f, 0.f, 0.f, 0.f};

    for (int k0 = 0; k0 < D_; k0 += 64) {
        __syncthreads();
        stage_rows(Ag + k0, Alds, lane, 2);     // A: 16 rows/wave (128 total)
        #pragma unroll
        for (int z = 0; z < 3; z++) {
            const ushort_t* Bg = Wqkvb + (size_t)z * WN
                               + (size_t)(n0 + wave * 8) * D_;
            stage_rows(Bg + k0, &Bs[z * 4096 + wave * 8 * 64], lane, 1);
        }
        __syncthreads();

        #pragma unroll
        for (int ksg = 0; ksg <= 4; ksg += 4) {
            const int kgo = ((ksg + quad) ^ (fr & 7)) << 3;
            bf16x8 af[2];
            #pragma unroll
            for (int i = 0; i < 2; i++) {
                uint4 u = *(const uint4*)&As[(wm + i * 16 + fr) * 64 + kgo];
                af[i] = __builtin_bit_cast(bf16x8, u);
            }
            #pragma unroll
            for (int z = 0; z < 3; z++) {
                bf16x8 bf[2];
                #pragma unroll
                for (int j2 = 0; j2 < 2; j2++) {
                    uint4 u = *(const uint4*)&Bs[z * 4096 + (wn + j2 * 16 + fr) * 64 + kgo];
                    bf[j2] = __builtin_bit_cast(bf16x8, u);
                }
                #pragma unroll
                for (int i = 0; i < 2; i++)
                    #pragma unroll
                    for (int j2 = 0; j2 < 2; j2++)
                        acc[z][i][j2] = __builtin_amdgcn_mfma_f32_16x16x32_bf16(
                            af[i], bf[j2], acc[z][i][j2], 0, 0, 0);
            }
        }
    }

    // epilogue: split heads, scalar bf16 stores
    #pragma unroll
    for (int z = 0; z < 3; z++) {
        const float* bi = (z == 0) ? bq : ((z == 1) ? bk : bv);
        ushort_t*    oz = qkv_ws + (size_t)z * (size_t)M_ * D_;
        #pragma unroll
        for (int j2 = 0; j2 < 2; j2++) {
            const int n = n0 + wn + j2 * 16 + fr;
            const float bias = bi[n];
            const int h  = n >> 6;
            const int hd = n & 63;
            #pragma unroll
            for (int i = 0; i < 2; i++) {
                #pragma unroll
                for (int rr = 0; rr < 4; rr++) {
                    const int m = m0 + wm + i * 16 + rb + rr;
                    const int b = m >> 11, t = m & (T_ - 1);
                    oz[(((size_t)(b * H_ + h)) * T_ + t) * HD_ + hd] =
                        f2bf(acc[z][i][j2][rr] + bias);
                }
            }
        }
    }
}

// Output projection (R1-proven config: 64x128 tile, 256 thr, grid 512).
__global__ __launch_bounds__(256) void gemm_out(
    const ushort_t* __restrict__ Yw, const ushort_t* __restrict__ Wob,
    const float* __restrict__ bo, float* __restrict__ out)
{
    const int flat = blockIdx.x;          // 0..511
    const int r    = flat & 7;
    const int j    = flat >> 3;           // 0..63
    const int mt   = ((r >> 1) << 4) | (j & 15);   // 0..63
    const int nt   = ((r & 1) << 2) | (j >> 4);    // 0..7

    __shared__ __align__(16) ushort_t As[64 * 64];
    __shared__ __align__(16) ushort_t Bs[128 * 64];

    const int tid  = threadIdx.x;
    const int m0   = mt * 64;
    const int n0   = nt * 128;
    const int wave = tid >> 6;
    const int lane = tid & 63;
    const int wm   = (wave >> 1) * 32;
    const int wn   = (wave & 1) * 64;
    const int fr   = lane & 15;
    const int quad = lane >> 4;

    const ushort_t* Ag = Yw  + (size_t)(m0 + wave * 16) * D_;
    const ushort_t* Bg = Wob + (size_t)(n0 + wave * 32) * D_;
    ushort_t* Alds = &As[wave * 16 * 64];
    ushort_t* Blds = &Bs[wave * 32 * 64];

    f32x4 acc[2][4];
    #pragma unroll
    for (int i = 0; i < 2; i++)
        #pragma unroll
        for (int j2 = 0; j2 < 4; j2++)
            acc[i][j2] = (f32x4){0.f, 0.f, 0.f, 0.f};

    for (int k0 = 0; k0 < D_; k0 += 64) {
        __syncthreads();
        stage_rows(Ag + k0, Alds, lane, 2);
        stage_rows(Bg + k0, Blds, lane, 4);
        __syncthreads();

        #pragma unroll
        for (int ksg = 0; ksg <= 4; ksg += 4) {
            const int kgo = ((ksg + quad) ^ (fr & 7)) << 3;
            bf16x8 af[2], bf[4];
            #pragma unroll
            for (int i = 0; i < 2; i++) {
                uint4 u = *(const uint4*)&As[(wm + i * 16 + fr) * 64 + kgo];
                af[i] = __builtin_bit_cast(bf16x8, u);
            }
            #pragma unroll
            for (int j2 = 0; j2 < 4; j2++) {
                uint4 u = *(const uint4*)&Bs[(wn + j2 * 16 + fr) * 64 + kgo];
                bf[j2] = __builtin_bit_cast(bf16x8, u);
            }
            #pragma unroll
            for (int i = 0; i < 2; i++)
                #pragma unroll
                for (int j2 = 0; j2 < 4; j2++)
                    acc[i][j2] = __builtin_amdgcn_mfma_f32_16x16x32_bf16(
                        af[i], bf[j2], acc[i][j2], 0, 0, 0);
        }
    }

    const int rb = quad * 4;
    #pragma unroll
    for (int j2 = 0; j2 < 4; j2++) {
        const int n = n0 + wn + j2 * 16 + fr;
        const float bias = bo[n];
        #pragma unroll
        for (int i = 0; i < 2; i++) {
            #pragma unroll
            for (int rr = 0; rr < 4; rr++) {
                const int m = m0 + wm + i * 16 + rb + rr;
                out[(size_t)m * D_ + n] = acc[i][j2][rr] + bias;
            }
        }
    }
}

#define LDS_ 136   // row stride (ushorts): 272 B = 68 dwords = 4-bank rotation

// swizzled transpose scatter from registers: uint4 g of [128][64] tile ->
// dst[row][blk*8 + s&7], blk = (sb&8) | ((sb ^ (row>>3)) & 7).  (proven)
__device__ inline void scatter_T(const uint4* u, ushort_t* dst, int tid) {
    #pragma unroll
    for (int g = 0; g < 4; g++) {
        const int v  = tid + 256 * g;
        const int s  = v >> 3;
        const int p8 = (v & 7) * 8;
        ushort_t e[8];
        *(uint4*)e = u[g];
        const int sb = s >> 3, slo = s & 7;
        #pragma unroll
        for (int j = 0; j < 8; j++) {
            const int p   = p8 + j;
            const int blk = (sb & 8) | ((sb ^ (p >> 3)) & 7);
            dst[p * LDS_ + (blk << 3) + slo] = e[j];
        }
    }
}

__device__ inline void stage_T(const ushort_t* __restrict__ src, ushort_t* dst, int tid) {
    uint4 u[4];
    #pragma unroll
    for (int g = 0; g < 4; g++) u[g] = ((const uint4*)src)[tid + 256 * g];
    scatter_T(u, dst, tid);
}

// 512-thread variant of stage_T (same swizzle, 2 groups of 512 uint4)
__device__ inline void stage_T512(const ushort_t* __restrict__ src, ushort_t* dst, int tid) {
    uint4 u[2];
    #pragma unroll
    for (int g = 0; g < 2; g++) u[g] = ((const uint4*)src)[tid + 512 * g];
    #pragma unroll
    for (int g = 0; g < 2; g++) {
        const int v  = tid + 512 * g;
        const int s  = v >> 3;
        const int p8 = (v & 7) * 8;
        ushort_t e[8];
        *(uint4*)e = u[g];
        const int sb = s >> 3, slo = s & 7;
        #pragma unroll
        for (int j = 0; j < 8; j++) {
            const int p   = p8 + j;
            const int blk = (sb & 8) | ((sb ^ (p >> 3)) & 7);
            dst[p * LDS_ + (blk << 3) + slo] = e[j];
        }
    }
}

// ---------------- per-chunk delta states (fully parallel over chunks) ----------------
// delta[bh][c][p][n] = sum_s V[s][p] * K[s][n]  (64x64, K-dim s=128), fp32 out.
__global__ __launch_bounds__(256) void chunk_delta(
    const ushort_t* __restrict__ k_ws, const ushort_t* __restrict__ v_ws,
    float* __restrict__ delta)
{
    const int c  = blockIdx.x;          // 0..15
    const int bh = blockIdx.y;          // 0..31
    __shared__ __align__(16) ushort_t VtS[64 * LDS_];   // V^T [p][s] swizzled
    __shared__ __align__(16) ushort_t KtS[64 * LDS_];   // K^T [n][s] swizzled

    const int tid  = threadIdx.x;
    const int wave = tid >> 6, lane = tid & 63;
    const int fr = lane & 15, quad = lane >> 4, rb = quad * 4;
    const int p  = wave * 16 + fr;

    const size_t base = ((size_t)bh * T_ + (size_t)c * CHK) * HD_;
    stage_T(v_ws + base, VtS, tid);
    stage_T(k_ws + base, KtS, tid);
    __syncthreads();

    f32x4 acc[4];
    #pragma unroll
    for (int jn = 0; jn < 4; jn++) acc[jn] = (f32x4){0.f, 0.f, 0.f, 0.f};

    #pragma unroll
    for (int kt = 0; kt < 4; kt++) {
        const int sb   = kt * 4 + quad;
        const int blkA = (sb & 8) | ((sb ^ (p >> 3)) & 7);
        bf16x8 af = __builtin_bit_cast(bf16x8,
            *(const uint4*)&VtS[p * LDS_ + (blkA << 3)]);
        #pragma unroll
        for (int jn = 0; jn < 4; jn++) {
            const int nr   = jn * 16 + fr;
            const int blkB = (sb & 8) | ((sb ^ (nr >> 3)) & 7);
            uint4 ub = *(const uint4*)&KtS[nr * LDS_ + (blkB << 3)];
            acc[jn] = __builtin_amdgcn_mfma_f32_16x16x32_bf16(
                af, __builtin_bit_cast(bf16x8, ub), acc[jn], 0, 0, 0);
        }
    }

    float* dp = delta + ((size_t)bh * NC + c) * 4096;
    #pragma unroll
    for (int jn = 0; jn < 4; jn++)
        #pragma unroll
        for (int r = 0; r < 4; r++)
            dp[(wave * 16 + rb + r) * 64 + jn * 16 + fr] = acc[jn][r];
}

// exclusive prefix over chunks, fp32 accumulate, emit bf16 states.
__global__ __launch_bounds__(256) void states_prefix(
    const float* __restrict__ delta, ushort_t* __restrict__ states_bf)
{
    const int qd = blockIdx.x;          // 0..3 (position quarter)
    const int bh = blockIdx.y;          // 0..31
    const size_t b0 = (size_t)bh * NC * 4096 + qd * 1024 + threadIdx.x;

    float s[4] = {0.f, 0.f, 0.f, 0.f};
    #pragma unroll
    for (int c = 0; c < NC; c++) {
        #pragma unroll
        for (int u = 0; u < 4; u++) {
            const size_t o = b0 + (size_t)c * 4096 + u * 256;
            states_bf[o] = f2bf(s[u]);
            s[u] += delta[o];
        }
    }
}

// ---------------- per-chunk attention (512 thr, 1 m-tile/wave) ----------------
__global__ __launch_bounds__(512) void attn_chunk(
    const ushort_t* __restrict__ q_ws, const ushort_t* __restrict__ k_ws,
    const ushort_t* __restrict__ v_ws, const ushort_t* __restrict__ states_bf,
    ushort_t* __restrict__ y_ws)
{
    const int c = blockIdx.x, bh = blockIdx.y;
    __shared__ __align__(16) ushort_t VtS[64 * LDS_];    // V^T [p][s] swizzled
    __shared__ __align__(16) ushort_t Smat[128 * LDS_];  // masked scores [t][s]

    const int tid  = threadIdx.x;
    const int wave = tid >> 6;        // 0..7 = m-tile
    const int lane = tid & 63;
    const int fr   = lane & 15;
    const int quad = lane >> 4;
    const int fk   = quad * 8;
    const int rb   = quad * 4;

    const size_t base = ((size_t)bh * T_ + (size_t)c * CHK) * HD_;
    const ushort_t* qg = q_ws + base;
    const ushort_t* kg = k_ws + base;
    const ushort_t* vg = v_ws + base;
    const ushort_t* st = states_bf + ((size_t)bh * NC + c) * 4096;

    stage_T512(vg, VtS, tid);
    __syncthreads();

    const int m = wave;

    bf16x8 aq[2];
    #pragma unroll
    for (int kk = 0; kk < 2; kk++) {
        uint4 u = *(const uint4*)(qg + (m * 16 + fr) * HD_ + kk * 32 + fk);
        aq[kk] = __builtin_bit_cast(bf16x8, u);
    }

    f32x4 acc[4];
    #pragma unroll
    for (int jn = 0; jn < 4; jn++) acc[jn] = (f32x4){0.f, 0.f, 0.f, 0.f};

    // inter-chunk: acc += Q . S_prev^T (bf16 states direct)
    #pragma unroll
    for (int jn = 0; jn < 4; jn++) {
        #pragma unroll
        for (int kk = 0; kk < 2; kk++) {
            uint4 u = *(const uint4*)(st + (jn * 16 + fr) * 64 + kk * 32 + fk);
            bf16x8 bsp = __builtin_bit_cast(bf16x8, u);
            acc[jn] = __builtin_amdgcn_mfma_f32_16x16x32_bf16(
                aq[kk], bsp, acc[jn], 0, 0, 0);
        }
    }

    // intra-chunk: scores -> mask -> Smat -> PV
    const int nk = (m + 2) >> 1;
    const int jt = 2 * nk;

    f32x4 sc[8];
    #pragma unroll
    for (int j = 0; j < 8; j++) sc[j] = (f32x4){0.f, 0.f, 0.f, 0.f};

    #pragma unroll
    for (int j = 0; j < 8; j++) {
        if (j <= m) {
            #pragma unroll
            for (int kk = 0; kk < 2; kk++) {
                uint4 u = *(const uint4*)(kg + (j * 16 + fr) * HD_ + kk * 32 + fk);
                sc[j] = __builtin_amdgcn_mfma_f32_16x16x32_bf16(
                    aq[kk], __builtin_bit_cast(bf16x8, u), sc[j], 0, 0, 0);
            }
        }
    }

    #pragma unroll
    for (int j = 0; j < 8; j++) {
        if (j < jt) {
            f32x4 v = sc[j];
            if (j == m) {
                #pragma unroll
                for (int r = 0; r < 4; r++)
                    if (fr > rb + r) v[r] = 0.f;
            }
            #pragma unroll
            for (int r = 0; r < 4; r++)
                Smat[(m * 16 + rb + r) * LDS_ + j * 16 + fr] = f2bf(v[r]);
        }
    }

    #pragma unroll
    for (int kt = 0; kt < 4; kt++) {
        if (kt < nk) {
            uint4 ua = *(const uint4*)&Smat[(m * 16 + fr) * LDS_ + kt * 32 + fk];
            bf16x8 as_ = __builtin_bit_cast(bf16x8, ua);
            #pragma unroll
            for (int jn = 0; jn < 4; jn++) {
                const int p   = jn * 16 + fr;
                const int sb  = kt * 4 + quad;
                const int blk = (sb & 8) | ((sb ^ (p >> 3)) & 7);
                uint4 ub = *(const uint4*)&VtS[p * LDS_ + (blk << 3)];
                acc[jn] = __builtin_amdgcn_mfma_f32_16x16x32_bf16(
                    as_, __builtin_bit_cast(bf16x8, ub), acc[jn], 0, 0, 0);
            }
        }
    }

    const int b = bh >> 4, h = bh & 15;
    ushort_t* yg = y_ws + ((size_t)(b * T_ + c * CHK)) * D_ + h * 64;
    #pragma unroll
    for (int jn = 0; jn < 4; jn++) {
        #pragma unroll
        for (int r = 0; r < 4; r++) {
            const int t = m * 16 + rb + r;
            const int p = jn * 16 + fr;
            yg[(size_t)t * D_ + p] = f2bf(acc[jn][r]);
        }
    }
}

// ---------------- launch ----------------
extern "C" void kernel_launch(void* const* d_in, const int* in_sizes, int n_in,
                              void* d_out, int out_size, void* d_ws, size_t ws_size,
                              hipStream_t stream)
{
    const float* x  = (const float*)d_in[0];
    const float* Wq = (const float*)d_in[1];
    const float* bq = (const float*)d_in[2];
    const float* Wk = (const float*)d_in[3];
    const float* bk = (const float*)d_in[4];
    const float* Wv = (const float*)d_in[5];
    const float* bv = (const float*)d_in[6];
    const float* Wo = (const float*)d_in[7];
    const float* bo = (const float*)d_in[8];
    float* out = (float*)d_out;

    // ws layout (ushort elems): [xb 4M][Wqb 1M][Wkb 1M][Wvb 1M][Wob 1M][q 4M][k 4M][v 4M][y 4M]
    // = 48 MB, then delta fp32 8 MB at +48 MB; states alias dead Wqb+Wkb.
    ushort_t* cvt    = (ushort_t*)d_ws;
    ushort_t* xb     = cvt;
    ushort_t* Wqkvb  = cvt + (size_t)XN;
    ushort_t* Wob    = cvt + (size_t)XN + 3 * WN;
    ushort_t* q_ws   = cvt + (size_t)XN + 4 * WN;
    ushort_t* k_ws   = q_ws + (size_t)M_ * D_;
    ushort_t* v_ws   = k_ws + (size_t)M_ * D_;
    ushort_t* y_ws   = v_ws + (size_t)M_ * D_;
    ushort_t* states_bf = Wqkvb;   // alias into dead Wqb+Wkb region, 4 MB
    float*    delta  = (float*)(y_ws + (size_t)M_ * D_);  // +48 MB, 8 MB fp32

    to_bf16_all<<<dim3((XN + 4 * WN) / 8 / 256), 256, 0, stream>>>(
        x, Wq, Wk, Wv, Wo, cvt);
    gemm_qkv<<<dim3(512), 512, 0, stream>>>(
        xb, Wqkvb, bq, bk, bv, q_ws);
    chunk_delta<<<dim3(NC, BH), 256, 0, stream>>>(k_ws, v_ws, delta);
    states_prefix<<<dim3(4, BH), 256, 0, stream>>>(delta, states_bf);
    attn_chunk<<<dim3(NC, BH), 512, 0, stream>>>(q_ws, k_ws, v_ws, states_bf, y_ws);
    gemm_out<<<dim3(512), 256, 0, stream>>>(y_ws, Wob, bo, out);
}